// Round 5
// baseline (725.525 us; speedup 1.0000x reference)
//
#include <hip/hip_runtime.h>

#define N_NODES 100000
#define NPAD    100096      // 782 * 128
#define NTILES  782
#define G_GRAPHS 256
#define IN_F 162
#define KPAD0 192
#define HID 128
#define R_REL 5
#define L_LAYERS 2
#define M5 (R_REL * N_NODES)

typedef __attribute__((ext_vector_type(8))) short bf16x8;
typedef __attribute__((ext_vector_type(4))) float f32x4;

__device__ __forceinline__ short f2bf(float f) {
    union { float f; unsigned u; } v; v.f = f;
    unsigned r = (v.u + 0x7fffu + ((v.u >> 16) & 1u)) >> 16;
    return (short)r;
}
__device__ __forceinline__ float bf2f(unsigned short u) {
    union { unsigned u; float f; } v; v.u = ((unsigned)u) << 16;
    return v.f;
}

// ---------------- CSR build (merged across relations, dst-major) ----------------
__global__ void k_count(const int* e0, const int* e1, const int* e2,
                        const int* e3, const int* e4, int* cnt, int E) {
    int gid = blockIdx.x * 256 + threadIdx.x;
    if (gid >= R_REL * E) return;
    int r = gid / E, e = gid - r * E;
    const int* ei = (r == 0) ? e0 : (r == 1) ? e1 : (r == 2) ? e2 : (r == 3) ? e3 : e4;
    atomicAdd(&cnt[r * N_NODES + ei[E + e]], 1);
}

__global__ __launch_bounds__(256) void k_scan1(const int* __restrict__ cnt,
                                               int* __restrict__ off, int* __restrict__ bsum) {
    __shared__ int ts[256];
    int t = threadIdx.x;
    int base = blockIdx.x * 1024 + t * 4;
    int v[4];
    #pragma unroll
    for (int j = 0; j < 4; j++) {
        int d = base + j;
        int s = 0;
        if (d < N_NODES) {
            #pragma unroll
            for (int r = 0; r < R_REL; r++) s += cnt[r * N_NODES + d];
        }
        v[j] = s;
    }
    int tsum = v[0] + v[1] + v[2] + v[3];
    ts[t] = tsum; __syncthreads();
    for (int o = 1; o < 256; o <<= 1) {
        int x = (t >= o) ? ts[t - o] : 0;
        __syncthreads();
        ts[t] += x;
        __syncthreads();
    }
    if (t == 255) bsum[blockIdx.x] = ts[255];
    int run = ts[t] - tsum;
    #pragma unroll
    for (int j = 0; j < 4; j++) { if (base + j < N_NODES) off[base + j] = run; run += v[j]; }
}

__global__ __launch_bounds__(512) void k_scan2(int* bsum, int nblk) {
    __shared__ int ts[512];
    int t = threadIdx.x;
    int v = (t < nblk) ? bsum[t] : 0;
    ts[t] = v; __syncthreads();
    for (int o = 1; o < 512; o <<= 1) {
        int x = (t >= o) ? ts[t - o] : 0;
        __syncthreads();
        ts[t] += x;
        __syncthreads();
    }
    if (t < nblk) bsum[t] = ts[t] - v;   // exclusive
}

__global__ void k_scan3(const int* __restrict__ off, const int* __restrict__ bsum,
                        int* __restrict__ mstart, int* __restrict__ mcur,
                        const int* __restrict__ cnt, float* __restrict__ invc) {
    int i = blockIdx.x * 256 + threadIdx.x;
    if (i >= N_NODES) return;
    int o = off[i] + bsum[i >> 10];
    mstart[i] = o;
    mcur[i] = o;
    int tc = 0;
    #pragma unroll
    for (int r = 0; r < R_REL; r++) {
        int c = cnt[r * N_NODES + i];
        tc += c;
        invc[r * N_NODES + i] = 1.0f / (float)max(c, 1);
    }
    if (i == N_NODES - 1) mstart[N_NODES] = o + tc;
}

// record = (src << 3) | relation
__global__ void k_fill(const int* e0, const int* e1, const int* e2,
                       const int* e3, const int* e4, int* mcur,
                       int* __restrict__ mrec, int E) {
    int gid = blockIdx.x * 256 + threadIdx.x;
    if (gid >= R_REL * E) return;
    int r = gid / E, e = gid - r * E;
    const int* ei = (r == 0) ? e0 : (r == 1) ? e1 : (r == 2) ? e2 : (r == 3) ? e3 : e4;
    int src = ei[e], dst = ei[E + e];
    int pos = atomicAdd(&mcur[dst], 1);
    mrec[pos] = (src << 3) | r;
}

// ---------------- X fp32 -> bf16, padded [NPAD][192] (zeros in pad) ----------------
__global__ void k_castX(const float* __restrict__ X, unsigned short* __restrict__ Xb) {
    int gid = blockIdx.x * 256 + threadIdx.x;
    if (gid >= NPAD * KPAD0) return;
    int row = gid / KPAD0, k = gid - row * KPAD0;
    float v = (row < N_NODES && k < IN_F) ? X[(size_t)row * IN_F + k] : 0.f;
    Xb[gid] = (unsigned short)f2bf(v);
}

// ---------------- weight pre-transpose (fp32 -> bf16, [seg][col][Kpad]) ----------------
__global__ void k_tw0(const float* __restrict__ root0, const float* __restrict__ W0,
                      short* __restrict__ out) {
    int gid = blockIdx.x * 256 + threadIdx.x;   // 6*128*192
    if (gid >= 6 * 128 * KPAD0) return;
    int chunk = gid / (128 * KPAD0);
    int rem = gid - chunk * 128 * KPAD0;
    int col = rem / KPAD0;
    int k = rem - col * KPAD0;
    float v = 0.f;
    if (k < IN_F)
        v = (chunk == 0) ? root0[k * HID + col]
                         : W0[((size_t)(chunk - 1) * IN_F + k) * HID + col];
    out[gid] = f2bf(v);
}

__global__ void k_twl(const float* __restrict__ rootl, const float* __restrict__ Wl,
                      short* __restrict__ out) {
    int gid = blockIdx.x * 256 + threadIdx.x;   // 2*6*128*128
    if (gid >= L_LAYERS * 6 * 128 * HID) return;
    int l = gid / (6 * 128 * HID);
    int rem = gid - l * 6 * 128 * HID;
    int chunk = rem / (128 * HID);
    int rem2 = rem - chunk * 128 * HID;
    int col = rem2 / HID;
    int k = rem2 - col * HID;
    float v = (chunk == 0) ? rootl[((size_t)l * HID + k) * HID + col]
                           : Wl[(((size_t)l * R_REL + (chunk - 1)) * HID + k) * HID + col];
    out[gid] = f2bf(v);
}

// ---------------- pre-aggregation: one wave per dst node, 5 relation accumulators ----------------
// Xagg[r][d][:] = mean over edges (src->d, rel r) of Xin[src][:]
// NS = bf16 elements per lane group: 2 (SEG=128) or 3 (SEG=192)
template<int NS, int SEG>
__global__ __launch_bounds__(256)
void aggregate_pre(const unsigned short* __restrict__ Xin, const int* __restrict__ mstart,
                   const int* __restrict__ mrec, const float* __restrict__ invc,
                   unsigned short* __restrict__ Xagg) {
    int wid = (blockIdx.x * 256 + threadIdx.x) >> 6;
    int lane = threadIdx.x & 63;
    if (wid >= N_NODES) return;
    int d = wid;
    int s = mstart[d], e = mstart[d + 1];

    float a0[R_REL], a1[R_REL], a2[R_REL];
    #pragma unroll
    for (int r = 0; r < R_REL; r++) { a0[r] = 0.f; a1[r] = 0.f; a2[r] = 0.f; }

    for (int base = s; base < e; base += 64) {
        int m = e - base;
        int rec = 0;
        if (lane < m) rec = mrec[base + lane];
        int cnt = min(m, 64);
        for (int j = 0; j < cnt; j++) {
            int rv = __shfl(rec, j, 64);
            int src = rv >> 3, r = rv & 7;
            const unsigned short* row = Xin + (size_t)src * SEG;
            unsigned u = *(const unsigned*)&row[2 * lane];
            float v0 = bf2f((unsigned short)(u & 0xffff));
            float v1 = bf2f((unsigned short)(u >> 16));
            float v2 = (NS == 3) ? bf2f(row[128 + lane]) : 0.f;
            #pragma unroll
            for (int rr = 0; rr < R_REL; rr++) {
                float msk = (rr == r) ? 1.f : 0.f;
                a0[rr] += msk * v0;
                a1[rr] += msk * v1;
                if (NS == 3) a2[rr] += msk * v2;
            }
        }
    }
    #pragma unroll
    for (int r = 0; r < R_REL; r++) {
        float w = invc[r * N_NODES + d];
        unsigned lo = (unsigned short)f2bf(a0[r] * w);
        unsigned hi = (unsigned short)f2bf(a1[r] * w);
        unsigned short* orow = Xagg + ((size_t)r * NPAD + d) * SEG;
        *(unsigned*)&orow[2 * lane] = lo | (hi << 16);
        if (NS == 3) orow[128 + lane] = (unsigned short)f2bf(a2[r] * w);
    }
}

// ---------------- fat GEMM: H = relu([X | Xagg0..4] @ Wfat + bias) ----------------
// K = 6*SEG; B staged seg-by-seg in a single LDS buffer; A direct-to-fragment.
template<int SEG>
__global__ __launch_bounds__(256)
void gemm_fat(const unsigned short* __restrict__ X0,    // seg 0, row stride SEG
              const unsigned short* __restrict__ Xagg,  // [5][NPAD][SEG]
              const short* __restrict__ Wt,             // [6][128 col][SEG]
              const float* __restrict__ bias,           // [128]
              unsigned short* __restrict__ H) {         // [NPAD][128]
    constexpr int KSEG = SEG / 32;
    constexpr int SA = SEG + 8;
    __shared__ short Bs[128 * SA];
    const int tid = threadIdx.x;
    const int row0 = blockIdx.x * 128;
    const int lane = tid & 63, wv = tid >> 6;
    const int quad = lane >> 4, l16 = lane & 15;
    const int wr0 = (wv >> 1) * 64, wc0 = (wv & 1) * 64;

    float bv[4];
    #pragma unroll
    for (int j = 0; j < 4; j++) bv[j] = bias[wc0 + j * 16 + l16];

    f32x4 acc[4][4];
    #pragma unroll
    for (int i = 0; i < 4; i++)
        #pragma unroll
        for (int j = 0; j < 4; j++) acc[i][j] = (f32x4){0.f, 0.f, 0.f, 0.f};

    const int arow = row0 + wr0 + l16;

    for (int seg = 0; seg < 6; seg++) {
        const unsigned short* Ap = (seg == 0) ? X0 : Xagg + (size_t)(seg - 1) * NPAD * SEG;
        // prefetch first A k-batch (independent of LDS)
        bf16x8 cur[4], nxt[4];
        #pragma unroll
        for (int i = 0; i < 4; i++)
            cur[i] = *(const bf16x8*)&Ap[(size_t)(arow + i * 16) * SEG + quad * 8];

        __syncthreads();   // previous segment's Bs readers done (no-op on seg 0)
        const short* Wc = Wt + (size_t)seg * 128 * SEG;
        for (int cidx = tid; cidx < 128 * (SEG / 8); cidx += 256) {
            int r = cidx / (SEG / 8), c8 = cidx - r * (SEG / 8);
            *(bf16x8*)&Bs[r * SA + c8 * 8] = *(const bf16x8*)&Wc[r * SEG + c8 * 8];
        }
        __syncthreads();

        for (int kb = 0; kb < KSEG; kb++) {
            if (kb + 1 < KSEG) {
                #pragma unroll
                for (int i = 0; i < 4; i++)
                    nxt[i] = *(const bf16x8*)&Ap[(size_t)(arow + i * 16) * SEG + (kb + 1) * 32 + quad * 8];
            }
            bf16x8 bfr[4];
            #pragma unroll
            for (int j = 0; j < 4; j++)
                bfr[j] = *(const bf16x8*)&Bs[(wc0 + j * 16 + l16) * SA + kb * 32 + quad * 8];
            #pragma unroll
            for (int i = 0; i < 4; i++)
                #pragma unroll
                for (int j = 0; j < 4; j++)
                    acc[i][j] = __builtin_amdgcn_mfma_f32_16x16x32_bf16(cur[i], bfr[j], acc[i][j], 0, 0, 0);
            #pragma unroll
            for (int i = 0; i < 4; i++) cur[i] = nxt[i];
        }
    }
    __syncthreads();

    // epilogue: bias + relu, acc -> Bs (bf16), full-line coalesced stores
    #pragma unroll
    for (int i = 0; i < 4; i++)
        #pragma unroll
        for (int j = 0; j < 4; j++)
            #pragma unroll
            for (int reg = 0; reg < 4; reg++) {
                float v = fmaxf(acc[i][j][reg] + bv[j], 0.f);
                Bs[(wr0 + i * 16 + quad * 4 + reg) * SA + wc0 + j * 16 + l16] = f2bf(v);
            }
    __syncthreads();

    #pragma unroll
    for (int s = 0; s < 8; s++) {
        int row = (tid >> 4) + s * 16;
        int col = (tid & 15) * 8;
        bf16x8 v = *(const bf16x8*)&Bs[row * SA + col];
        *(bf16x8*)&H[(size_t)(row0 + row) * HID + col] = v;
    }
}

// ---------------- readout ----------------
__global__ __launch_bounds__(128)
void k_pool(const unsigned short* __restrict__ h, const int* __restrict__ batch,
            float* __restrict__ pooled) {
    int c = threadIdx.x;
    int start = blockIdx.x * 128;
    if (start >= N_NODES) return;
    int end = min(start + 128, N_NODES);
    int g = batch[start];
    float s = 0.f;
    for (int i = start; i < end; i++) {
        int gi = batch[i];
        if (gi != g) { atomicAdd(&pooled[g * HID + c], s); s = 0.f; g = gi; }
        s += bf2f(h[(size_t)i * HID + c]);
    }
    atomicAdd(&pooled[g * HID + c], s);
}

__device__ int lower_bound_i(const int* a, int n, int v) {
    int lo = 0, hi = n;
    while (lo < hi) {
        int mid = (lo + hi) >> 1;
        if (a[mid] < v) lo = mid + 1; else hi = mid;
    }
    return lo;
}

__global__ __launch_bounds__(128)
void k_mlp(const float* __restrict__ pooled, const int* __restrict__ batch,
           const float* __restrict__ Wc1, const float* __restrict__ bc1,
           const float* __restrict__ Wc2, const float* __restrict__ bc2,
           const float* __restrict__ Wc3, const float* __restrict__ bc3,
           float* __restrict__ out) {
    int g = blockIdx.x;
    int c = threadIdx.x;
    __shared__ int range[2];
    if (c == 0) range[0] = lower_bound_i(batch, N_NODES, g);
    if (c == 1) range[1] = lower_bound_i(batch, N_NODES, g + 1);
    __syncthreads();
    float denom = fmaxf((float)(range[1] - range[0]), 1.0f);
    __shared__ float row[HID], h1[HID], h2[HID];
    row[c] = pooled[g * HID + c] / denom;
    __syncthreads();
    float acc = bc1[c];
    for (int k = 0; k < HID; k++) acc += row[k] * Wc1[k * HID + c];
    h1[c] = fmaxf(acc, 0.f);
    __syncthreads();
    acc = bc2[c];
    for (int k = 0; k < HID; k++) acc += h1[k] * Wc2[k * HID + c];
    h2[c] = fmaxf(acc, 0.f);
    __syncthreads();
    float t = h2[c] * Wc3[c];
    for (int off = 32; off > 0; off >>= 1) t += __shfl_down(t, off, 64);
    __shared__ float part[2];
    if ((c & 63) == 0) part[c >> 6] = t;
    __syncthreads();
    if (c == 0) out[g] = part[0] + part[1] + bc3[0];
}

// ---------------- launcher ----------------
extern "C" void kernel_launch(void* const* d_in, const int* in_sizes, int n_in,
                              void* d_out, int out_size, void* d_ws, size_t ws_size,
                              hipStream_t stream) {
    const float* X     = (const float*)d_in[0];
    const int*   batch = (const int*)d_in[1];
    const int*   e0 = (const int*)d_in[2];
    const int*   e1 = (const int*)d_in[3];
    const int*   e2 = (const int*)d_in[4];
    const int*   e3 = (const int*)d_in[5];
    const int*   e4 = (const int*)d_in[6];
    const float* W0    = (const float*)d_in[7];
    const float* root0 = (const float*)d_in[8];
    const float* b0    = (const float*)d_in[9];
    const float* Wl    = (const float*)d_in[10];
    const float* rootl = (const float*)d_in[11];
    const float* bl    = (const float*)d_in[12];
    const float* Wc1   = (const float*)d_in[13];
    const float* bc1   = (const float*)d_in[14];
    const float* Wc2   = (const float*)d_in[15];
    const float* bc2   = (const float*)d_in[16];
    const float* Wc3   = (const float*)d_in[17];
    const float* bc3   = (const float*)d_in[18];
    const int E = in_sizes[2] / 2;
    const int NE = R_REL * E;

    char* base = (char*)d_ws;
    size_t o = 0;
    auto carve = [&](size_t bytes) -> char* {
        char* p = base + o;
        o = (o + bytes + 255) & ~(size_t)255;
        return p;
    };
    // xagg region sized for layer 0 (SEG=192); layers 1-2 use SEG=128 -> first 5*NPAD*128
    // shorts only, so hB aliases the dead tail at offset 5*NPAD*128 shorts.
    unsigned short* xagg = (unsigned short*)carve((size_t)R_REL * NPAD * KPAD0 * 2);
    unsigned short* hB   = xagg + (size_t)R_REL * NPAD * HID;   // alias (safe; see lifetimes)
    unsigned short* hA   = (unsigned short*)carve((size_t)NPAD * HID * 2);
    unsigned short* Xb   = (unsigned short*)carve((size_t)NPAD * KPAD0 * 2);
    int*   cnt    = (int*)carve((size_t)M5 * 4);
    float* invc   = (float*)carve((size_t)M5 * 4);
    int*   offsc  = (int*)carve((size_t)N_NODES * 4);
    int*   mstart = (int*)carve((size_t)(N_NODES + 1) * 4);
    int*   mcur   = (int*)carve((size_t)N_NODES * 4);
    int*   mrec   = (int*)carve((size_t)NE * 4);
    int*   bsum   = (int*)carve(2048);
    float* pooled = (float*)carve((size_t)G_GRAPHS * HID * 4);
    short* Wt0    = (short*)carve((size_t)6 * 128 * KPAD0 * 2);
    short* Wtl    = (short*)carve((size_t)L_LAYERS * 6 * 128 * HID * 2);

    // ---- CSR build + casts ----
    hipMemsetAsync(cnt, 0, (size_t)M5 * 4, stream);
    hipMemsetAsync(pooled, 0, (size_t)G_GRAPHS * HID * 4, stream);
    int eg = (NE + 255) / 256;
    k_count<<<eg, 256, 0, stream>>>(e0, e1, e2, e3, e4, cnt, E);
    int nblk = (N_NODES + 1023) / 1024;   // 98
    k_scan1<<<nblk, 256, 0, stream>>>(cnt, offsc, bsum);
    k_scan2<<<1, 512, 0, stream>>>(bsum, nblk);
    k_scan3<<<(N_NODES + 255) / 256, 256, 0, stream>>>(offsc, bsum, mstart, mcur, cnt, invc);
    k_fill<<<eg, 256, 0, stream>>>(e0, e1, e2, e3, e4, mcur, mrec, E);
    k_castX<<<(NPAD * KPAD0 + 255) / 256, 256, 0, stream>>>(X, Xb);
    k_tw0<<<(6 * 128 * KPAD0 + 255) / 256, 256, 0, stream>>>(root0, W0, Wt0);
    k_twl<<<(L_LAYERS * 6 * 128 * HID + 255) / 256, 256, 0, stream>>>(rootl, Wl, Wtl);

    int agg_grid = (N_NODES + 3) / 4;     // one wave per node, 4 waves/block

    // ---- layer 0: aggregate X (SEG=192), fat GEMM K=1152 -> hA ----
    aggregate_pre<3, KPAD0><<<agg_grid, 256, 0, stream>>>(Xb, mstart, mrec, invc, xagg);
    gemm_fat<KPAD0><<<NTILES, 256, 0, stream>>>(Xb, xagg, Wt0, b0, hA);

    // ---- layer 1: hA -> hB (hB aliases xagg tail, disjoint from SEG=128 reads) ----
    aggregate_pre<2, HID><<<agg_grid, 256, 0, stream>>>(hA, mstart, mrec, invc, xagg);
    gemm_fat<HID><<<NTILES, 256, 0, stream>>>(hA, xagg, Wtl, bl, hB);

    // ---- layer 2: hB -> hA ----
    aggregate_pre<2, HID><<<agg_grid, 256, 0, stream>>>(hB, mstart, mrec, invc, xagg);
    gemm_fat<HID><<<NTILES, 256, 0, stream>>>(hB, xagg, Wtl + (size_t)6 * 128 * HID,
                                              bl + HID, hA);

    // ---- readout ----
    k_pool<<<(N_NODES + 127) / 128, 128, 0, stream>>>(hA, batch, pooled);
    k_mlp<<<G_GRAPHS, 128, 0, stream>>>(pooled, batch, Wc1, bc1, Wc2, bc2, Wc3, bc3, (float*)d_out);
}